// Round 4
// baseline (727.985 us; speedup 1.0000x reference)
//
#include <hip/hip_runtime.h>
#include <hip/hip_cooperative_groups.h>
#include <math.h>

namespace cg = cooperative_groups;

#define BB 8
#define HH 128
#define WW 128
#define DD 512
#define GRID (BB * HH)   // 1024 blocks = 4 blocks/CU * 256 CU co-resident at VGPR<=64
#define THR 512
// region geometry: region_h = 32, stride 24, 4 regions, all 32x32 (1024 px)

typedef __attribute__((ext_vector_type(4))) float fvec4;

__device__ __forceinline__ float4 f4z() { return make_float4(0.f, 0.f, 0.f, 0.f); }
__device__ __forceinline__ float4 f4add(float4 a, float4 b) {
    return make_float4(a.x + b.x, a.y + b.y, a.z + b.z, a.w + b.w);
}
__device__ __forceinline__ float4 f4fma(float s, float4 a, float4 acc) {
    return make_float4(fmaf(s, a.x, acc.x), fmaf(s, a.y, acc.y),
                       fmaf(s, a.z, acc.z), fmaf(s, a.w, acc.w));
}
__device__ __forceinline__ float4 f4scale(float4 a, float s) {
    return make_float4(a.x * s, a.y * s, a.z * s, a.w * s);
}

// ---------------------------------------------------------------------------
// p1: per (b,h) row, 4 overlapping column-strip sums + row total.
// 512 threads: dt = tid&127 owns float4 d-slice, g = tid>>7 owns w mod 4.
// DE-LOCKSTEP: block starts its 8 KiB-chunk walk at rot = bh&31 (wraps).
// All resident blocks otherwise read the same offset within their 256 KiB
// rows simultaneously -> few HBM channels -> 1.38 TB/s (measured round 2).
// Strip membership via wave-uniform 0/1 mask FMAs (exact; mult is 1.0/0.0).
// Normal (caching) loads: seeds L3 (features = 256 MiB = L3 size) for p3.
// ---------------------------------------------------------------------------
__device__ __forceinline__ void p1_row(const float* __restrict__ f,
                                       float* __restrict__ rowpart,
                                       float* __restrict__ rowtot,
                                       int bh, int tid, float4 (*lds1)[5][128]) {
    const int dt = tid & 127;
    const int g = tid >> 7;
    const int d4 = dt * 4;
    const int rot = bh & 31;

    const float4* p = (const float4*)(f + (size_t)bh * WW * DD) + (size_t)g * (DD / 4) + dt;

    float4 tot = f4z(), r0 = f4z(), r1 = f4z(), r2 = f4z(), r3 = f4z();

#pragma unroll
    for (int k = 0; k < 32; ++k) {
        int it = k + rot;
        it = (it >= 32) ? (it - 32) : it;                 // wave-uniform
        const float4 v = p[(size_t)it * 4 * (DD / 4)];
        // strip j covers it in [6j, 6j+8)
        const float m0 = ((unsigned)it < 8u) ? 1.0f : 0.0f;
        const float m1 = ((unsigned)(it - 6) < 8u) ? 1.0f : 0.0f;
        const float m2 = ((unsigned)(it - 12) < 8u) ? 1.0f : 0.0f;
        const float m3 = ((unsigned)(it - 18) < 8u) ? 1.0f : 0.0f;
        tot = f4add(tot, v);
        r0 = f4fma(m0, v, r0);
        r1 = f4fma(m1, v, r1);
        r2 = f4fma(m2, v, r2);
        r3 = f4fma(m3, v, r3);
    }

    // merge the 4 w-groups through LDS (group 0 accumulates groups 1..3)
    if (g > 0) {
        lds1[g - 1][0][dt] = r0;
        lds1[g - 1][1][dt] = r1;
        lds1[g - 1][2][dt] = r2;
        lds1[g - 1][3][dt] = r3;
        lds1[g - 1][4][dt] = tot;
    }
    __syncthreads();
    if (g == 0) {
#pragma unroll
        for (int gg = 0; gg < 3; ++gg) {
            r0 = f4add(r0, lds1[gg][0][dt]);
            r1 = f4add(r1, lds1[gg][1][dt]);
            r2 = f4add(r2, lds1[gg][2][dt]);
            r3 = f4add(r3, lds1[gg][3][dt]);
            tot = f4add(tot, lds1[gg][4][dt]);
        }
        float4* rp = (float4*)(rowpart + ((size_t)bh * 4) * DD + d4);
        rp[0 * (DD / 4)] = r0;
        rp[1 * (DD / 4)] = r1;
        rp[2 * (DD / 4)] = r2;
        rp[3 * (DD / 4)] = r3;
        *(float4*)(rowtot + (size_t)bh * DD + d4) = tot;
    }
}

// ---------------------------------------------------------------------------
// p2: reduce rows -> region means (/1024) and global mean (/16384).
// Active blocks 0..BB*17-1. 512 threads: dt owns d4, q = tid>>7 row-quarter.
// ---------------------------------------------------------------------------
__device__ __forceinline__ void p2_all(const float* __restrict__ rowpart,
                                       const float* __restrict__ rowtot,
                                       float* __restrict__ means,
                                       float* __restrict__ gmean,
                                       int blk, int tid, float4 (*l2buf)[128]) {
    if (blk >= BB * 17) return;
    const int b = blk / 17;
    const int o = blk % 17;
    const int dt = tid & 127;
    const int q = tid >> 7;
    const int d4 = dt * 4;

    float4 s = f4z();
    if (o < 16) {
        const int i = o >> 2;
        const int j = o & 3;
        const int h0 = i * 24;
#pragma unroll
        for (int hh = 0; hh < 8; ++hh) {
            const int bh = b * HH + h0 + q * 8 + hh;
            s = f4add(s, *(const float4*)(rowpart + ((size_t)bh * 4 + j) * DD + d4));
        }
    } else {
#pragma unroll 8
        for (int hh = 0; hh < 32; ++hh) {
            const int bh = b * HH + q * 32 + hh;
            s = f4add(s, *(const float4*)(rowtot + (size_t)bh * DD + d4));
        }
    }
    if (q > 0) l2buf[q - 1][dt] = s;
    __syncthreads();
    if (q == 0) {
#pragma unroll
        for (int qq = 0; qq < 3; ++qq) s = f4add(s, l2buf[qq][dt]);
        if (o < 16)
            *(float4*)(means + ((size_t)b * 16 + o) * DD + d4) = f4scale(s, 1.0f / 1024.0f);
        else
            *(float4*)(gmean + (size_t)b * DD + d4) = f4scale(s, 1.0f / (float)(HH * WW));
    }
}

// ---------------------------------------------------------------------------
// p3: per-pixel output for one (b,h) row, same rot = bh&31 de-lockstep walk.
// Feature loads non-temporal (last use; hit the L3 lines p1 allocated).
// Output stores non-temporal (never re-read; don't evict features from L3).
// ---------------------------------------------------------------------------
__device__ __forceinline__ void p3_row(const float* __restrict__ f,
                                       const float* __restrict__ means,
                                       const float* __restrict__ gmean,
                                       float* __restrict__ out,
                                       int bh, int b, int tid,
                                       const float4* sww, const float* hwv) {
    const int dt = tid & 127;
    const int g = tid >> 7;
    const int d4 = dt * 4;
    const int rot = bh & 31;

    // per-thread column-combined means: cs[j] = sum_i hw[i]*m[b, i*4+j, d4..d4+3]
    float4 cs0 = f4z(), cs1 = f4z(), cs2 = f4z(), cs3 = f4z();
#pragma unroll
    for (int i = 0; i < 4; ++i) {
        const float hwi = hwv[i];
        const float4* mrow = (const float4*)(means + ((size_t)b * 16 + i * 4) * DD + d4);
        cs0 = f4fma(hwi, mrow[0 * (DD / 4)], cs0);
        cs1 = f4fma(hwi, mrow[1 * (DD / 4)], cs1);
        cs2 = f4fma(hwi, mrow[2 * (DD / 4)], cs2);
        cs3 = f4fma(hwi, mrow[3 * (DD / 4)], cs3);
    }
    const float4 gv = *(const float4*)(gmean + (size_t)b * DD + d4);
    const float4 gterm = f4scale(gv, 0.4f);  // (1-rw)*global, rw=0.6

    const float* fp = f + (size_t)bh * WW * DD + (size_t)g * DD + d4;
    float* op = out + (size_t)bh * WW * DD + (size_t)g * DD + d4;

#pragma unroll
    for (int k = 0; k < 32; ++k) {
        int it = k + rot;
        it = (it >= 32) ? (it - 32) : it;         // wave-uniform
        const int w = it * 4 + g;
        const fvec4 v = __builtin_nontemporal_load((const fvec4*)(fp + (size_t)it * 4 * DD));
        const float4 wwv = sww[w];                // LDS broadcast (inv pre-folded)
        fvec4 o;
        o.x = v.x + gterm.x + (cs0.x * wwv.x + cs1.x * wwv.y + cs2.x * wwv.z + cs3.x * wwv.w);
        o.y = v.y + gterm.y + (cs0.y * wwv.x + cs1.y * wwv.y + cs2.y * wwv.z + cs3.y * wwv.w);
        o.z = v.z + gterm.z + (cs0.z * wwv.x + cs1.z * wwv.y + cs2.z * wwv.z + cs3.z * wwv.w);
        o.w = v.w + gterm.w + (cs0.w * wwv.x + cs1.w * wwv.y + cs2.w * wwv.z + cs3.w * wwv.w);
        __builtin_nontemporal_store(o, (fvec4*)(op + (size_t)it * 4 * DD));
    }
}

// ---------------------------------------------------------------------------
// fused cooperative kernel: full problem in one dispatch.
// 1024 blocks x 512 threads, 4 blocks/CU (VGPR<=64 forced, LDS 38 KiB <= 40).
// p1(all 8 batches) -> grid.sync -> p2 -> grid.sync -> p3(all 8 batches).
// ---------------------------------------------------------------------------
__global__ __launch_bounds__(THR, 8) void fused_all(const float* __restrict__ f,
                                                    float* __restrict__ rowpart,
                                                    float* __restrict__ rowtot,
                                                    float* __restrict__ means,
                                                    float* __restrict__ gmean,
                                                    float* __restrict__ out) {
    __shared__ float4 lds1[3][5][128];   // p1 merge (30720 B)
    __shared__ float4 l2buf[3][128];     // p2 merge (6144 B)
    __shared__ float4 sww[WW];           // p3 w-weight table (2048 B)

    cg::grid_group grid = cg::this_grid();
    const int blk = blockIdx.x;
    const int tid = threadIdx.x;
    const int b = blk >> 7;
    const int h = blk & 127;

    // weight tables once (h fixed per block)
    const float hc = (3.0f / 127.0f) * (float)h;
    float hwv[4];
    float Hs = 0.f;
#pragma unroll
    for (int i = 0; i < 4; ++i) {
        const float t = (hc - (float)i) * 0.25f;
        hwv[i] = __expf(-2.0f * t * t);
        Hs += hwv[i];
    }
    if (tid < WW) {
        const float wc = (3.0f / 127.0f) * (float)tid;
        float wv[4];
        float Ws = 0.f;
#pragma unroll
        for (int j = 0; j < 4; ++j) {
            const float t = (wc - (float)j) * 0.25f;
            wv[j] = __expf(-2.0f * t * t);
            Ws += wv[j];
        }
        const float inv = 0.6f / (Hs * Ws + 1e-8f);
        sww[tid] = make_float4(wv[0] * inv, wv[1] * inv, wv[2] * inv, wv[3] * inv);
    }
    __syncthreads();

    p1_row(f, rowpart, rowtot, blk, tid, lds1);
    grid.sync();
    p2_all(rowpart, rowtot, means, gmean, blk, tid, l2buf);
    grid.sync();
    p3_row(f, means, gmean, out, blk, b, tid, sww, hwv);
}

// ===========================================================================
// Fallback 3-kernel path (proven: 481 us total incl. harness fills).
// ===========================================================================
__global__ __launch_bounds__(512) void k1_rowsums(const float* __restrict__ f,
                                                  float* __restrict__ rowpart,
                                                  float* __restrict__ rowtot) {
    __shared__ float4 lds1[3][5][128];
    p1_row(f, rowpart, rowtot, blockIdx.x, threadIdx.x, lds1);
}

__global__ __launch_bounds__(512) void k2_reduce(const float* __restrict__ rowpart,
                                                 const float* __restrict__ rowtot,
                                                 float* __restrict__ means,
                                                 float* __restrict__ gmean) {
    __shared__ float4 l2buf[3][128];
    p2_all(rowpart, rowtot, means, gmean, blockIdx.x, threadIdx.x, l2buf);
}

__global__ __launch_bounds__(512) void k3_output(const float* __restrict__ f,
                                                 const float* __restrict__ means,
                                                 const float* __restrict__ gmean,
                                                 float* __restrict__ out) {
    __shared__ float4 sww[WW];
    const int bh = blockIdx.x;
    const int b = bh / HH;
    const int h = bh % HH;
    const int tid = threadIdx.x;

    const float hc = (3.0f / 127.0f) * (float)h;
    float hwv[4];
    float Hs = 0.f;
#pragma unroll
    for (int i = 0; i < 4; ++i) {
        const float t = (hc - (float)i) * 0.25f;
        hwv[i] = __expf(-2.0f * t * t);
        Hs += hwv[i];
    }
    if (tid < WW) {
        const float wc = (3.0f / 127.0f) * (float)tid;
        float wv[4];
        float Ws = 0.f;
#pragma unroll
        for (int j = 0; j < 4; ++j) {
            const float t = (wc - (float)j) * 0.25f;
            wv[j] = __expf(-2.0f * t * t);
            Ws += wv[j];
        }
        const float inv = 0.6f / (Hs * Ws + 1e-8f);
        sww[tid] = make_float4(wv[0] * inv, wv[1] * inv, wv[2] * inv, wv[3] * inv);
    }
    __syncthreads();
    p3_row(f, means, gmean, out, bh, b, tid, sww, hwv);
}

extern "C" void kernel_launch(void* const* d_in, const int* in_sizes, int n_in,
                              void* d_out, int out_size, void* d_ws, size_t ws_size,
                              hipStream_t stream) {
    const float* f = (const float*)d_in[0];
    float* out = (float*)d_out;

    // workspace layout (floats): rowpart | rowtot | means | gmean  (~10.4 MiB)
    float* ws = (float*)d_ws;
    float* rowpart = ws;                                   // B*H*4*D
    float* rowtot = rowpart + (size_t)BB * HH * 4 * DD;    // B*H*D
    float* means = rowtot + (size_t)BB * HH * DD;          // B*16*D
    float* gmean = means + (size_t)BB * 16 * DD;           // B*D

    void* args[] = {(void*)&f, (void*)&rowpart, (void*)&rowtot,
                    (void*)&means, (void*)&gmean, (void*)&out};
    hipError_t e = hipLaunchCooperativeKernel((const void*)fused_all, dim3(GRID),
                                              dim3(THR), args, 0, stream);
    if (e != hipSuccess) {
        // fallback: proven 3-kernel path
        k1_rowsums<<<BB * HH, 512, 0, stream>>>(f, rowpart, rowtot);
        k2_reduce<<<BB * 17, 512, 0, stream>>>(rowpart, rowtot, means, gmean);
        k3_output<<<BB * HH, 512, 0, stream>>>(f, means, gmean, out);
    }
}

// Round 6
// 480.882 us; speedup vs baseline: 1.5139x; 1.5139x over previous
//
#include <hip/hip_runtime.h>
#include <math.h>

#define BB 8
#define HH 128
#define WW 128
#define DD 512
// region geometry: region_h = 32, stride 24, 4 regions, all 32x32 (1024 px)
// rows split into half-rows (w in [0,64), [64,128)): 2048 blocks oversubscribe
// the 1024 co-resident slots 2x -> load-balance the HBM-service tail.

typedef __attribute__((ext_vector_type(4))) float fvec4;

__device__ __forceinline__ float4 f4z() { return make_float4(0.f, 0.f, 0.f, 0.f); }
__device__ __forceinline__ float4 f4add(float4 a, float4 b) {
    return make_float4(a.x + b.x, a.y + b.y, a.z + b.z, a.w + b.w);
}
__device__ __forceinline__ float4 f4fma(float s, float4 a, float4 acc) {
    return make_float4(fmaf(s, a.x, acc.x), fmaf(s, a.y, acc.y),
                       fmaf(s, a.z, acc.z), fmaf(s, a.w, acc.w));
}
__device__ __forceinline__ float4 f4scale(float4 a, float s) {
    return make_float4(a.x * s, a.y * s, a.z * s, a.w * s);
}

// ---------------------------------------------------------------------------
// k1: per (bh, half) half-row: strip partial sums + half-row total.
// 512 threads: dt = tid&127 owns float4 d-slice, g = tid>>7 owns w mod 4.
// 16 iterations of 8 KiB chunks, walk rotated by blk&15 (de-lockstep).
// Strip j covers global it in [6j, 6j+8); branchless 0/1-mask FMAs (exact).
// Normal loads: seeds L3 (features = 256 MiB = L3 size) for k3's re-read.
// rowpart layout: [bh][half][4 strips][D]; rowtot: [bh][half][D].
// ---------------------------------------------------------------------------
__global__ __launch_bounds__(512) void k1_rowsums(const float* __restrict__ f,
                                                  float* __restrict__ rowpart,
                                                  float* __restrict__ rowtot) {
    const int blk = blockIdx.x;           // 2 * bh + half
    const int bh = blk >> 1;
    const int half = blk & 1;
    const int tid = threadIdx.x;
    const int dt = tid & 127;
    const int g = tid >> 7;
    const int d4 = dt * 4;
    const int rot = blk & 15;

    // chunk il covers w = half*64 + [4*il, 4*il+4); this thread reads (w=..+g, d4)
    const float4* p = (const float4*)(f + (size_t)bh * WW * DD + (size_t)half * 64 * DD)
                      + (size_t)g * (DD / 4) + dt;

    float4 tot = f4z(), r0 = f4z(), r1 = f4z(), r2 = f4z(), r3 = f4z();

#pragma unroll
    for (int k = 0; k < 16; ++k) {
        const int il = (k + rot) & 15;                    // block-uniform
        const int it = half * 16 + il;                    // global chunk index
        const float4 v = p[(size_t)il * 4 * (DD / 4)];
        const float m0 = ((unsigned)it < 8u) ? 1.0f : 0.0f;
        const float m1 = ((unsigned)(it - 6) < 8u) ? 1.0f : 0.0f;
        const float m2 = ((unsigned)(it - 12) < 8u) ? 1.0f : 0.0f;
        const float m3 = ((unsigned)(it - 18) < 8u) ? 1.0f : 0.0f;
        tot = f4add(tot, v);
        r0 = f4fma(m0, v, r0);
        r1 = f4fma(m1, v, r1);
        r2 = f4fma(m2, v, r2);
        r3 = f4fma(m3, v, r3);
    }

    // merge the 4 w-groups through LDS (group 0 accumulates groups 1..3)
    __shared__ float4 lds[3][5][128];
    if (g > 0) {
        lds[g - 1][0][dt] = r0;
        lds[g - 1][1][dt] = r1;
        lds[g - 1][2][dt] = r2;
        lds[g - 1][3][dt] = r3;
        lds[g - 1][4][dt] = tot;
    }
    __syncthreads();
    if (g == 0) {
#pragma unroll
        for (int gg = 0; gg < 3; ++gg) {
            r0 = f4add(r0, lds[gg][0][dt]);
            r1 = f4add(r1, lds[gg][1][dt]);
            r2 = f4add(r2, lds[gg][2][dt]);
            r3 = f4add(r3, lds[gg][3][dt]);
            tot = f4add(tot, lds[gg][4][dt]);
        }
        float4* rp = (float4*)(rowpart + ((size_t)blk * 4) * DD + d4);
        rp[0 * (DD / 4)] = r0;
        rp[1 * (DD / 4)] = r1;
        rp[2 * (DD / 4)] = r2;
        rp[3 * (DD / 4)] = r3;
        *(float4*)(rowtot + (size_t)blk * DD + d4) = tot;
    }
}

// ---------------------------------------------------------------------------
// k2: reduce half-row partials -> region means (/1024), global mean (/16384).
// 136 blocks x 512 threads: b = blk/17, o = blk%17 (16 regions + 1 global).
// dt owns d4; q = tid>>7 owns a quarter of the rows; LDS merge.
// ---------------------------------------------------------------------------
__global__ __launch_bounds__(512) void k2_reduce(const float* __restrict__ rowpart,
                                                 const float* __restrict__ rowtot,
                                                 float* __restrict__ means,
                                                 float* __restrict__ gmean) {
    const int blk = blockIdx.x;
    const int b = blk / 17;
    const int o = blk % 17;
    const int tid = threadIdx.x;
    const int dt = tid & 127;
    const int q = tid >> 7;
    const int d4 = dt * 4;

    float4 s = f4z();
    if (o < 16) {
        const int i = o >> 2;
        const int j = o & 3;
        const int h0 = i * 24;
#pragma unroll
        for (int hh = 0; hh < 8; ++hh) {
            const int bh = b * HH + h0 + q * 8 + hh;
#pragma unroll
            for (int half = 0; half < 2; ++half) {
                s = f4add(s, *(const float4*)(rowpart +
                        ((size_t)(bh * 2 + half) * 4 + j) * DD + d4));
            }
        }
    } else {
#pragma unroll 8
        for (int hh = 0; hh < 32; ++hh) {
            const int bh = b * HH + q * 32 + hh;
#pragma unroll
            for (int half = 0; half < 2; ++half) {
                s = f4add(s, *(const float4*)(rowtot + (size_t)(bh * 2 + half) * DD + d4));
            }
        }
    }
    __shared__ float4 l2buf[3][128];
    if (q > 0) l2buf[q - 1][dt] = s;
    __syncthreads();
    if (q == 0) {
#pragma unroll
        for (int qq = 0; qq < 3; ++qq) s = f4add(s, l2buf[qq][dt]);
        if (o < 16)
            *(float4*)(means + ((size_t)b * 16 + o) * DD + d4) = f4scale(s, 1.0f / 1024.0f);
        else
            *(float4*)(gmean + (size_t)b * DD + d4) = f4scale(s, 1.0f / (float)(HH * WW));
    }
}

// ---------------------------------------------------------------------------
// k3: per-pixel output, half-row blocks, same rotation. Feature loads NT
// (last use; hit the L3 lines k1 allocated). Output stores NT (never
// re-read; don't evict features from L3).
// ---------------------------------------------------------------------------
__global__ __launch_bounds__(512) void k3_output(const float* __restrict__ f,
                                                 const float* __restrict__ means,
                                                 const float* __restrict__ gmean,
                                                 float* __restrict__ out) {
    const int blk = blockIdx.x;
    const int bh = blk >> 1;
    const int half = blk & 1;
    const int b = bh >> 7;
    const int h = bh & 127;
    const int tid = threadIdx.x;
    const int dt = tid & 127;
    const int g = tid >> 7;
    const int d4 = dt * 4;
    const int rot = blk & 15;

    __shared__ float4 sww[WW];   // (ww0..ww3) * 0.6/(Hs*Ws+1e-8) per w

    const float hc = (3.0f / 127.0f) * (float)h;
    float hwv[4];
    float Hs = 0.f;
#pragma unroll
    for (int i = 0; i < 4; ++i) {
        const float t = (hc - (float)i) * 0.25f;
        hwv[i] = __expf(-2.0f * t * t);
        Hs += hwv[i];
    }
    if (tid < WW) {
        const float wc = (3.0f / 127.0f) * (float)tid;
        float wv[4];
        float Ws = 0.f;
#pragma unroll
        for (int j = 0; j < 4; ++j) {
            const float t = (wc - (float)j) * 0.25f;
            wv[j] = __expf(-2.0f * t * t);
            Ws += wv[j];
        }
        const float inv = 0.6f / (Hs * Ws + 1e-8f);
        sww[tid] = make_float4(wv[0] * inv, wv[1] * inv, wv[2] * inv, wv[3] * inv);
    }
    __syncthreads();

    // cs[j] = sum_i hw[i] * means[b, i*4+j, d4..d4+3]
    float4 cs0 = f4z(), cs1 = f4z(), cs2 = f4z(), cs3 = f4z();
#pragma unroll
    for (int i = 0; i < 4; ++i) {
        const float hwi = hwv[i];
        const float4* mrow = (const float4*)(means + ((size_t)b * 16 + i * 4) * DD + d4);
        cs0 = f4fma(hwi, mrow[0 * (DD / 4)], cs0);
        cs1 = f4fma(hwi, mrow[1 * (DD / 4)], cs1);
        cs2 = f4fma(hwi, mrow[2 * (DD / 4)], cs2);
        cs3 = f4fma(hwi, mrow[3 * (DD / 4)], cs3);
    }
    const float4 gv = *(const float4*)(gmean + (size_t)b * DD + d4);
    const float4 gterm = f4scale(gv, 0.4f);  // (1-rw)*global, rw=0.6

    const float* fp = f + (size_t)bh * WW * DD + (size_t)half * 64 * DD + (size_t)g * DD + d4;
    float* op = out + (size_t)bh * WW * DD + (size_t)half * 64 * DD + (size_t)g * DD + d4;

#pragma unroll
    for (int k = 0; k < 16; ++k) {
        const int il = (k + rot) & 15;                // block-uniform
        const int w = half * 64 + il * 4 + g;
        const fvec4 v = __builtin_nontemporal_load((const fvec4*)(fp + (size_t)il * 4 * DD));
        const float4 wwv = sww[w];                    // LDS broadcast
        fvec4 o;
        o.x = v.x + gterm.x + (cs0.x * wwv.x + cs1.x * wwv.y + cs2.x * wwv.z + cs3.x * wwv.w);
        o.y = v.y + gterm.y + (cs0.y * wwv.x + cs1.y * wwv.y + cs2.y * wwv.z + cs3.y * wwv.w);
        o.z = v.z + gterm.z + (cs0.z * wwv.x + cs1.z * wwv.y + cs2.z * wwv.z + cs3.z * wwv.w);
        o.w = v.w + gterm.w + (cs0.w * wwv.x + cs1.w * wwv.y + cs2.w * wwv.z + cs3.w * wwv.w);
        __builtin_nontemporal_store(o, (fvec4*)(op + (size_t)il * 4 * DD));
    }
}

extern "C" void kernel_launch(void* const* d_in, const int* in_sizes, int n_in,
                              void* d_out, int out_size, void* d_ws, size_t ws_size,
                              hipStream_t stream) {
    const float* f = (const float*)d_in[0];
    float* out = (float*)d_out;

    // workspace (floats): rowpart [B*H*2*4*D] | rowtot [B*H*2*D] | means | gmean
    float* ws = (float*)d_ws;
    float* rowpart = ws;                                       // 16.8 MiB
    float* rowtot = rowpart + (size_t)BB * HH * 2 * 4 * DD;    // 4.2 MiB
    float* means = rowtot + (size_t)BB * HH * 2 * DD;          // 256 KiB
    float* gmean = means + (size_t)BB * 16 * DD;               // 16 KiB

    k1_rowsums<<<BB * HH * 2, 512, 0, stream>>>(f, rowpart, rowtot);
    k2_reduce<<<BB * 17, 512, 0, stream>>>(rowpart, rowtot, means, gmean);
    k3_output<<<BB * HH * 2, 512, 0, stream>>>(f, means, gmean, out);
}